// Round 7
// baseline (160.016 us; speedup 1.0000x reference)
//
#include <hip/hip_runtime.h>

#define C_DIM 64
#define K_CODES 1024

#define QUANT_OFF 0
#define LOSS_OFF  4194304
#define IDX_OFF   4194306

// ws layout (bytes): [0..8) double loss-sum; [64..4160) 0.5*|cb|^2 (1024 f32);
// [8192..401408) stream: 32 chunks x 12 segs x 1024 B (bf16 negated splits, 32 codes/chunk)
#define WS_CBSQH_F 16
#define WS_STREAM_B 8192
#define SEG_BYTES 1024
#define CHUNK_BYTES 12288
#define N_CHUNKS 32
#define WS_NEEDED (WS_STREAM_B + N_CHUNKS * CHUNK_BYTES)

typedef float floatx16 __attribute__((ext_vector_type(16)));
typedef short bf16x8  __attribute__((ext_vector_type(8)));

typedef __attribute__((address_space(1))) const void gv_t;
typedef __attribute__((address_space(3))) void lv_t;

static __device__ inline unsigned short f2bf(float v) {
    unsigned int u = __float_as_uint(v);
    unsigned int r = (u + 0x7FFF + ((u >> 16) & 1)) >> 16;   // RNE
    return (unsigned short)r;
}
static __device__ inline float bf2f(unsigned short b) {
    return __uint_as_float(((unsigned int)b) << 16);
}

// ---------------- prep: cb -> negated bf16 split stream + 0.5*|cb|^2 ----------------
// grid 400 x 64: blocks 0..383 = (chunk 0..31, seg 0..11); 384..399 = cb_sq.
__global__ void vq_prep(const float* __restrict__ cb, float* __restrict__ ws)
{
    const int tid = threadIdx.x;               // 0..63
    const int blk = blockIdx.x;
    if (blk >= 384) {
        int code = (blk - 384) * 64 + tid;
        const float4* row = reinterpret_cast<const float4*>(cb + code * C_DIM);
        float s = 0.f;
        #pragma unroll
        for (int j = 0; j < 16; ++j) {
            float4 v = row[j];
            s = fmaf(v.x, v.x, s); s = fmaf(v.y, v.y, s);
            s = fmaf(v.z, v.z, s); s = fmaf(v.w, v.w, s);
        }
        ws[WS_CBSQH_F + code] = 0.5f * s;
        return;
    }
    const int chunk = blk / 12;                // 0..31 (uniform scalar div)
    const int seg   = blk - chunk * 12;        // 0..11 = tb*4 + s4
    const int tb = seg >> 2;
    const int s4 = seg & 3;
    const int code = chunk * 32 + (tid & 31);
    const int c0   = s4 * 16 + ((tid >> 5) << 3);
    const float* src = cb + code * C_DIM + c0;
    unsigned short us[8];
    #pragma unroll
    for (int j = 0; j < 8; ++j) {
        float v  = src[j];
        float h  = bf2f(f2bf(v));
        float r1 = v - h;                 // exact
        float m  = bf2f(f2bf(r1));
        float r2 = r1 - m;                // exact
        float sel = (tb == 0) ? h : (tb == 1) ? m : r2;
        us[j] = f2bf(-sel);               // negated: MFMA yields -dot
    }
    uint4 o;
    o.x = (unsigned)us[0] | ((unsigned)us[1] << 16);
    o.y = (unsigned)us[2] | ((unsigned)us[3] << 16);
    o.z = (unsigned)us[4] | ((unsigned)us[5] << 16);
    o.w = (unsigned)us[6] | ((unsigned)us[7] << 16);
    *reinterpret_cast<uint4*>((char*)ws + WS_STREAM_B + chunk * CHUNK_BYTES
                              + seg * SEG_BYTES + tid * 16) = o;
}

// ---------------- main: codes-as-A (LDS), tokens-as-B (regs), 8 waves ----------------
__global__ __launch_bounds__(512, 4) void vq_main(
    const float* __restrict__ x,      // [64][64][32][32]
    const float* __restrict__ cb,     // [1024][64] fp32 (epilogue gather)
    const float* __restrict__ ws_f,
    float* __restrict__ out,
    double* __restrict__ ws_sum)
{
    __shared__ __align__(16) char smem[49152];   // x-stage fp32 [64][130] (33.3KB) then 4x12KB A-bufs
    __shared__ float cbsqh_s[K_CODES];           // 4 KB
    __shared__ float redv[2][128];
    __shared__ int   redi[2][128];
    __shared__ int   kidx_s[128];

    const int tid  = threadIdx.x;                // 0..511
    const int tok0 = blockIdx.x * 128;
    const int b    = tok0 >> 10;
    const int hw0  = tok0 & 1023;

    const int w   = tid >> 6;       // wave 0..7
    const int ln  = tid & 63;
    const int tw  = w >> 1;         // token tile 0..3 (32 tokens each)
    const int kw  = w & 1;          // code half: chunks 2i+kw
    const int l31 = ln & 31;
    const int l5  = ln >> 5;

    // ---- stage x tile [c][token] fp32; load cbsq/2 ----
    float* xs = reinterpret_cast<float*>(smem);   // [64][130]
    #pragma unroll
    for (int j = 0; j < 16; ++j) {
        int idx = j * 512 + tid;
        int c = idx >> 7, t = idx & 127;
        xs[c * 130 + t] = x[((b * C_DIM + c) << 10) + hw0 + t];
    }
    cbsqh_s[tid]       = ws_f[WS_CBSQH_F + tid];
    cbsqh_s[tid + 512] = ws_f[WS_CBSQH_F + tid + 512];
    __syncthreads();

    // ---- build token B-fragments (3-term split): tf[term][s4] ----
    // B layout (32x32x16): col = l&31 (token), k = (l>>5)*8 + j
    bf16x8 tf[3][4];
    {
        const int token = tw * 32 + l31;
        #pragma unroll
        for (int s4 = 0; s4 < 4; ++s4) {
            const int cb0 = s4 * 16 + l5 * 8;
            #pragma unroll
            for (int j = 0; j < 8; ++j) {
                float v  = xs[(cb0 + j) * 130 + token];
                float h  = bf2f(f2bf(v));
                float r1 = v - h;                 // exact
                float m  = bf2f(f2bf(r1));
                float r2 = r1 - m;                // exact
                tf[0][s4][j] = (short)f2bf(h);
                tf[1][s4][j] = (short)f2bf(m);
                tf[2][s4][j] = (short)f2bf(r2);
            }
        }
    }
    __syncthreads();   // xs dead; smem becomes A-buffers [p][dbuf] = p*24576 + d*12288

    const char* stream = (const char*)ws_f + WS_STREAM_B;

    // stage chunks 0 (->buf[0][0]) and 1 (->buf[1][0]); each wave 3 of 24 segs
    #pragma unroll
    for (int it = 0; it < 3; ++it) {
        int s  = w * 3 + it;          // 0..23
        int p  = s / 12;              // chunk parity
        int si = s - p * 12;
        const char* g = stream + p * CHUNK_BYTES + si * SEG_BYTES + ln * 16;
        __builtin_amdgcn_global_load_lds((gv_t*)g,
            (lv_t*)(smem + p * 24576 + si * SEG_BYTES + ln * 16), 16, 0, 0);
    }
    __syncthreads();

    float minv = 3.4e38f;
    int   mini = 0;

    #pragma unroll 1
    for (int i = 0; i < 16; ++i) {
        // prefetch chunks 2(i+1)+{0,1} into dbuf slot (i+1)&1
        if (i < 15) {
            #pragma unroll
            for (int it = 0; it < 3; ++it) {
                int s  = w * 3 + it;
                int p  = s / 12;
                int si = s - p * 12;
                const char* g = stream + (2 * (i + 1) + p) * CHUNK_BYTES + si * SEG_BYTES + ln * 16;
                __builtin_amdgcn_global_load_lds((gv_t*)g,
                    (lv_t*)(smem + p * 24576 + ((i + 1) & 1) * CHUNK_BYTES + si * SEG_BYTES + ln * 16),
                    16, 0, 0);
            }
        }

        const char* abase = smem + kw * 24576 + (i & 1) * CHUNK_BYTES;
        floatx16 accA, accB;
        #pragma unroll
        for (int r = 0; r < 16; ++r) { accA[r] = 0.f; accB[r] = 0.f; }

        #pragma unroll
        for (int tb = 0; tb < 3; ++tb) {
            #pragma unroll
            for (int s4 = 0; s4 < 4; ++s4) {
                bf16x8 as = *reinterpret_cast<const bf16x8*>(
                    abase + (tb * 4 + s4) * SEG_BYTES + ln * 16);
                #pragma unroll
                for (int a = 0; a < 3; ++a) {
                    if (a + tb <= 2) {            // 6 split-products
                        if (((a + s4) & 1) == 0)
                            accA = __builtin_amdgcn_mfma_f32_32x32x16_bf16(as, tf[a][s4], accA, 0, 0, 0);
                        else
                            accB = __builtin_amdgcn_mfma_f32_32x32x16_bf16(as, tf[a][s4], accB, 0, 0, 0);
                    }
                }
            }
        }

        // per-lane argmin over this chunk's 16 rows (codes); idx ascends -> strict <
        const int chbase = (2 * i + kw) * 32;
        const float* cp = &cbsqh_s[chbase + 4 * l5];
        float4 cq0 = *reinterpret_cast<const float4*>(cp);
        float4 cq1 = *reinterpret_cast<const float4*>(cp + 8);
        float4 cq2 = *reinterpret_cast<const float4*>(cp + 16);
        float4 cq3 = *reinterpret_cast<const float4*>(cp + 24);
        float cqa[16] = {cq0.x, cq0.y, cq0.z, cq0.w, cq1.x, cq1.y, cq1.z, cq1.w,
                         cq2.x, cq2.y, cq2.z, cq2.w, cq3.x, cq3.y, cq3.z, cq3.w};
        #pragma unroll
        for (int r = 0; r < 16; ++r) {
            float v = accA[r] + accB[r] + cqa[r];          // 0.5|c|^2 - dot
            int idx = chbase + 8 * (r >> 2) + 4 * l5 + (r & 3);
            if (v < minv) { minv = v; mini = idx; }
        }

        __syncthreads();   // drains prefetch (vmcnt 0) + protects buffer reuse
    }

    // ---- merge l5 halves within wave, then code-halves across waves ----
    {
        float ov = __shfl_xor(minv, 32, 64);
        int   oi = __shfl_xor(mini, 32, 64);
        if (ov < minv || (ov == minv && oi < mini)) { minv = ov; mini = oi; }
        if (ln < 32) {
            redv[kw][tw * 32 + ln] = minv;
            redi[kw][tw * 32 + ln] = mini;
        }
    }
    __syncthreads();

    if (tid < 128) {
        float v0 = redv[0][tid]; int i0 = redi[0][tid];
        float v1 = redv[1][tid]; int i1 = redi[1][tid];
        int bi = (v1 < v0 || (v1 == v0 && i1 < i0)) ? i1 : i0;
        kidx_s[tid] = bi;
        out[IDX_OFF + tok0 + tid] = (float)bi;
    }
    __syncthreads();

    // ---- epilogue: quant (STE form) + loss partial; x re-read from global ----
    {
        const int i  = tid & 127;
        const int c0 = tid >> 7;                  // 0..3, 16 channels each
        const int kk = kidx_s[i];
        const float* crow = cb + kk * C_DIM;      // L2-resident gather
        float lsum = 0.f;
        #pragma unroll
        for (int j = 0; j < 16; ++j) {
            int c = c0 * 16 + j;
            float q  = crow[c];
            float xv = x[((b * C_DIM + c) << 10) + hw0 + i];
            float d  = q - xv;                    // (quant - xt)
            lsum = fmaf(d, d, lsum);
            out[QUANT_OFF + ((b * C_DIM + c) << 10) + hw0 + i] = xv + d;  // xt + sg(q-x)
        }
        #pragma unroll
        for (int off = 32; off > 0; off >>= 1)
            lsum += __shfl_down(lsum, off, 64);
        if ((tid & 63) == 0)
            atomicAdd(ws_sum, (double)lsum);
    }
}

// ---------------- fallback (round-2-verified VALU path, used if ws too small) ----------------
#define CB_PAD 68
__global__ __launch_bounds__(256, 2) void vq_main_valu(
    const float* __restrict__ x,
    const float* __restrict__ cb,
    float* __restrict__ out,
    double* __restrict__ ws_sum)
{
    __shared__ float xt_s[C_DIM][128];
    __shared__ float cb_s[C_DIM][CB_PAD];
    __shared__ float cbsq_all[K_CODES];
    __shared__ float red_v[8][128];
    __shared__ int   red_i[8][128];
    __shared__ int   kidx_s[128];

    const int tid  = threadIdx.x;
    const int tok0 = blockIdx.x * 128;
    const int b_img = tok0 >> 10;
    const int hw0   = tok0 & 1023;

    #pragma unroll
    for (int r = 0; r < 4; ++r) {
        int k = tid + r * 256;
        const float4* row = reinterpret_cast<const float4*>(cb + k * C_DIM);
        float s = 0.f;
        #pragma unroll
        for (int j = 0; j < 16; ++j) {
            float4 v = row[j];
            s = fmaf(v.x, v.x, s); s = fmaf(v.y, v.y, s);
            s = fmaf(v.z, v.z, s); s = fmaf(v.w, v.w, s);
        }
        cbsq_all[k] = s;
    }
    {
        const int i  = tid & 127;
        const int c0 = tid >> 7;
        #pragma unroll
        for (int j = 0; j < 32; ++j) {
            int c = c0 + 2 * j;
            xt_s[c][i] = x[((b_img * C_DIM + c) << 10) + hw0 + i];
        }
    }

    const int tl = tid & 31;
    const int kg = tid >> 5;
    float minv[4]; int mini[4];
    #pragma unroll
    for (int m = 0; m < 4; ++m) { minv[m] = 3.4e38f; mini[m] = 0; }

    for (int ch = 0; ch < 16; ++ch) {
        __syncthreads();
        for (int t = tid; t < 64 * C_DIM; t += 256) {
            int kl = t >> 6, c = t & 63;
            cb_s[c][kl] = cb[(ch * 64 + kl) * C_DIM + c];
        }
        __syncthreads();
        float dot[4][8];
        #pragma unroll
        for (int m = 0; m < 4; ++m)
            #pragma unroll
            for (int k = 0; k < 8; ++k) dot[m][k] = 0.f;
        #pragma unroll 4
        for (int c = 0; c < C_DIM; ++c) {
            float4 xv  = *reinterpret_cast<const float4*>(&xt_s[c][tl * 4]);
            float4 cv0 = *reinterpret_cast<const float4*>(&cb_s[c][kg * 8]);
            float4 cv1 = *reinterpret_cast<const float4*>(&cb_s[c][kg * 8 + 4]);
            float xa[4] = {xv.x, xv.y, xv.z, xv.w};
            float ca[8] = {cv0.x, cv0.y, cv0.z, cv0.w, cv1.x, cv1.y, cv1.z, cv1.w};
            #pragma unroll
            for (int m = 0; m < 4; ++m)
                #pragma unroll
                for (int k = 0; k < 8; ++k)
                    dot[m][k] = fmaf(xa[m], ca[k], dot[m][k]);
        }
        const int codebase = ch * 64 + kg * 8;
        #pragma unroll
        for (int k = 0; k < 8; ++k) {
            float csq = cbsq_all[codebase + k];
            #pragma unroll
            for (int m = 0; m < 4; ++m) {
                float sc = fmaf(-2.f, dot[m][k], csq);
                if (sc < minv[m]) { minv[m] = sc; mini[m] = codebase + k; }
            }
        }
    }
    #pragma unroll
    for (int m = 0; m < 4; ++m) {
        red_v[kg][tl * 4 + m] = minv[m];
        red_i[kg][tl * 4 + m] = mini[m];
    }
    __syncthreads();
    if (tid < 128) {
        float bv = red_v[0][tid]; int bi = red_i[0][tid];
        #pragma unroll
        for (int g = 1; g < 8; ++g) {
            float v = red_v[g][tid]; int ii = red_i[g][tid];
            if (v < bv || (v == bv && ii < bi)) { bv = v; bi = ii; }
        }
        kidx_s[tid] = bi;
        out[IDX_OFF + tok0 + tid] = (float)bi;
    }
    __syncthreads();
    {
        const int i  = tid & 127;
        const int c0 = tid >> 7;
        const int kk = kidx_s[i];
        const float* crow = cb + kk * C_DIM;
        float lsum = 0.f;
        #pragma unroll
        for (int j = 0; j < 32; ++j) {
            int c = c0 * 32 + j;
            float q  = crow[c];
            float xv = xt_s[c][i];
            float d  = q - xv;
            lsum = fmaf(d, d, lsum);
            out[QUANT_OFF + ((b_img * C_DIM + c) << 10) + hw0 + i] = xv + d;
        }
        #pragma unroll
        for (int off = 32; off > 0; off >>= 1)
            lsum += __shfl_down(lsum, off, 64);
        if ((tid & 63) == 0)
            atomicAdd(ws_sum, (double)lsum);
    }
}

__global__ void vq_finalize(const double* __restrict__ ws_sum,
                            float* __restrict__ out)
{
    float m = (float)(ws_sum[0] / 4194304.0);
    out[LOSS_OFF]     = m;   // loss_embed
    out[LOSS_OFF + 1] = m;   // loss_commitment (identical forward value)
}

extern "C" void kernel_launch(void* const* d_in, const int* in_sizes, int n_in,
                              void* d_out, int out_size, void* d_ws, size_t ws_size,
                              hipStream_t stream) {
    const float* x  = (const float*)d_in[0];
    const float* cb = (const float*)d_in[1];
    float* out      = (float*)d_out;

    hipMemsetAsync(d_ws, 0, sizeof(double), stream);
    if (ws_size >= (size_t)WS_NEEDED) {
        vq_prep<<<400, 64, 0, stream>>>(cb, (float*)d_ws);
        vq_main<<<512, 512, 0, stream>>>(x, cb, (const float*)d_ws, out, (double*)d_ws);
    } else {
        vq_main_valu<<<512, 256, 0, stream>>>(x, cb, out, (double*)d_ws);
    }
    vq_finalize<<<1, 1, 0, stream>>>((const double*)d_ws, out);
}

// Round 9
// 140.647 us; speedup vs baseline: 1.1377x; 1.1377x over previous
//
#include <hip/hip_runtime.h>

#define C_DIM 64
#define K_CODES 1024

#define QUANT_OFF 0
#define LOSS_OFF  4194304
#define IDX_OFF   4194306

// ws layout (bytes): [0..64) 8 double loss-sums; [64..4160) 0.5*|cb|^2 (1024 f32);
// [8192..270336) stream: 32 chunks x 8 segs x 1024 B (fp16 negated 2-way splits, 32 codes/chunk)
#define WS_CBSQH_F 16
#define WS_STREAM_B 8192
#define SEG_BYTES 1024
#define CHUNK_BYTES 8192
#define N_CHUNKS 32
#define WS_NEEDED (WS_STREAM_B + N_CHUNKS * CHUNK_BYTES)

typedef float floatx16 __attribute__((ext_vector_type(16)));
typedef _Float16 fp16x8 __attribute__((ext_vector_type(8)));

typedef __attribute__((address_space(1))) const void gv_t;
typedef __attribute__((address_space(3))) void lv_t;

static __device__ inline unsigned short h2u(_Float16 h) {
    union { _Float16 f; unsigned short u; } c; c.f = h; return c.u;
}

// ---------------- prep: cb -> negated fp16 2-split stream + 0.5*|cb|^2 + zero sums ----------------
// grid 272 x 64: blocks 0..255 = (chunk 0..31, seg 0..7); 256..271 = cb_sq (block 271 zeros sums).
__global__ void vq_prep(const float* __restrict__ cb, float* __restrict__ ws)
{
    const int tid = threadIdx.x;               // 0..63
    const int blk = blockIdx.x;
    if (blk >= 256) {
        if (blk == 271 && tid < 8)
            reinterpret_cast<double*>(ws)[tid] = 0.0;
        int code = (blk - 256) * 64 + tid;
        const float4* row = reinterpret_cast<const float4*>(cb + code * C_DIM);
        float s = 0.f;
        #pragma unroll
        for (int j = 0; j < 16; ++j) {
            float4 v = row[j];
            s = fmaf(v.x, v.x, s); s = fmaf(v.y, v.y, s);
            s = fmaf(v.z, v.z, s); s = fmaf(v.w, v.w, s);
        }
        ws[WS_CBSQH_F + code] = 0.5f * s;
        return;
    }
    const int chunk = blk >> 3;                // 0..31
    const int seg   = blk & 7;                 // tb*4 + s4
    const int tb = seg >> 2;
    const int s4 = seg & 3;
    const int code = chunk * 32 + (tid & 31);
    const int c0   = s4 * 16 + ((tid >> 5) << 3);
    const float* src = cb + code * C_DIM + c0;
    unsigned short us[8];
    #pragma unroll
    for (int j = 0; j < 8; ++j) {
        float v = src[j];
        _Float16 h = (_Float16)v;             // RNE
        float r = v - (float)h;               // exact residual (Sterbenz)
        _Float16 sel = (tb == 0) ? (_Float16)(-v) : (_Float16)(-r);
        us[j] = h2u(sel);                     // negated: MFMA yields -dot
    }
    uint4 o;
    o.x = (unsigned)us[0] | ((unsigned)us[1] << 16);
    o.y = (unsigned)us[2] | ((unsigned)us[3] << 16);
    o.z = (unsigned)us[4] | ((unsigned)us[5] << 16);
    o.w = (unsigned)us[6] | ((unsigned)us[7] << 16);
    *reinterpret_cast<uint4*>((char*)ws + WS_STREAM_B + chunk * CHUNK_BYTES
                              + seg * SEG_BYTES + tid * 16) = o;
}

// ---------------- main: codes-as-A (LDS dbuf, 4 chunks/phase), tokens-as-B (regs fp16) ----------------
__global__ __launch_bounds__(512, 4) void vq_main(
    const float* __restrict__ x,      // [64][64][32][32]
    const float* __restrict__ cb,     // [1024][64] fp32 (epilogue gather)
    const float* __restrict__ ws_f,
    float* __restrict__ out,
    double* __restrict__ ws_sum)
{
    __shared__ __align__(16) char smem[65536];   // x-stage fp32 [64][132] (33.8KB), then 2 slots x 32KB
    __shared__ float cbsqh_s[K_CODES];           // 4 KB
    __shared__ float redv[2][128];
    __shared__ int   redi[2][128];
    __shared__ int   kidx_s[128];

    const int tid  = threadIdx.x;                // 0..511
    const int tok0 = blockIdx.x * 128;
    const int b    = tok0 >> 10;
    const int hw0  = tok0 & 1023;

    const int w   = tid >> 6;       // wave 0..7
    const int ln  = tid & 63;
    const int tw  = w >> 1;         // token tile 0..3 (32 tokens each)
    const int kw  = w & 1;          // per phase: chunk-pair 2kw,2kw+1 of the 4 staged
    const int l31 = ln & 31;
    const int l5  = ln >> 5;

    // ---- stage x tile [c][token] fp32 (float4) + cbsq/2 ----
    float* xs = reinterpret_cast<float*>(smem);   // [64][132]
    #pragma unroll
    for (int j = 0; j < 4; ++j) {
        int idx = j * 512 + tid;                  // 0..2047
        int c   = idx >> 5;
        int t4  = (idx & 31) << 2;
        float4 v = *reinterpret_cast<const float4*>(&x[((b * C_DIM + c) << 10) + hw0 + t4]);
        *reinterpret_cast<float4*>(&xs[c * 132 + t4]) = v;
    }
    cbsqh_s[tid]       = ws_f[WS_CBSQH_F + tid];
    cbsqh_s[tid + 512] = ws_f[WS_CBSQH_F + tid + 512];
    __syncthreads();

    // ---- build token B-fragments (fp16 2-split): tf[term][s4] ----
    // B layout (32x32x16): col = l&31 (token), k = (l>>5)*8 + j
    fp16x8 tf[2][4];
    {
        const int token = tw * 32 + l31;
        #pragma unroll
        for (int s4 = 0; s4 < 4; ++s4) {
            const int cb0 = s4 * 16 + l5 * 8;
            #pragma unroll
            for (int j = 0; j < 8; ++j) {
                float v = xs[(cb0 + j) * 132 + token];
                _Float16 h = (_Float16)v;         // RNE
                float r = v - (float)h;           // exact
                tf[0][s4][j] = h;
                tf[1][s4][j] = (_Float16)r;
            }
        }
    }
    __syncthreads();   // xs dead; smem = A slots: slot*32768 + cl*8192 + seg*1024

    const char* stream = (const char*)ws_f + WS_STREAM_B;

    // stage chunks 0..3 into slot 0; each wave 4 of 32 segs
    #pragma unroll
    for (int it = 0; it < 4; ++it) {
        int s  = w * 4 + it;          // 0..31
        int cl = s >> 3;              // chunk-local 0..3
        int si = s & 7;
        const char* g = stream + cl * CHUNK_BYTES + si * SEG_BYTES + ln * 16;
        __builtin_amdgcn_global_load_lds((gv_t*)g,
            (lv_t*)(smem + cl * CHUNK_BYTES + si * SEG_BYTES + ln * 16), 16, 0, 0);
    }
    __syncthreads();

    float minv = 3.4e38f;
    int   mini = 0;

    #pragma unroll 1
    for (int i = 0; i < 8; ++i) {
        // prefetch chunks 4(i+1)..4(i+1)+3 into slot (i+1)&1
        if (i < 7) {
            #pragma unroll
            for (int it = 0; it < 4; ++it) {
                int s  = w * 4 + it;
                int cl = s >> 3;
                int si = s & 7;
                const char* g = stream + (4 * (i + 1) + cl) * CHUNK_BYTES + si * SEG_BYTES + ln * 16;
                __builtin_amdgcn_global_load_lds((gv_t*)g,
                    (lv_t*)(smem + (((i + 1) & 1) * 32768) + cl * CHUNK_BYTES + si * SEG_BYTES + ln * 16),
                    16, 0, 0);
            }
        }

        // two sub-chunks (32 codes each) for this wave
        #pragma unroll
        for (int sub = 0; sub < 2; ++sub) {
            const int cl = 2 * kw + sub;
            const char* abase = smem + (i & 1) * 32768 + cl * CHUNK_BYTES;
            const int chbase = (4 * i + cl) * 32;

            // acc p0 initialized with 0.5|c|^2 (saves the add later)
            const float* cp = &cbsqh_s[chbase + 4 * l5];
            float4 cq0 = *reinterpret_cast<const float4*>(cp);
            float4 cq1 = *reinterpret_cast<const float4*>(cp + 8);
            float4 cq2 = *reinterpret_cast<const float4*>(cp + 16);
            float4 cq3 = *reinterpret_cast<const float4*>(cp + 24);
            floatx16 p0, p1, p2;
            p0[0] = cq0.x; p0[1] = cq0.y; p0[2]  = cq0.z; p0[3]  = cq0.w;
            p0[4] = cq1.x; p0[5] = cq1.y; p0[6]  = cq1.z; p0[7]  = cq1.w;
            p0[8] = cq2.x; p0[9] = cq2.y; p0[10] = cq2.z; p0[11] = cq2.w;
            p0[12] = cq3.x; p0[13] = cq3.y; p0[14] = cq3.z; p0[15] = cq3.w;
            #pragma unroll
            for (int r = 0; r < 16; ++r) { p1[r] = 0.f; p2[r] = 0.f; }

            // 3 independent chains (depth 4): hh' -> p0, h_c*r_x -> p1, r_c*h_x -> p2
            #pragma unroll
            for (int s4 = 0; s4 < 4; ++s4) {
                fp16x8 a0 = *reinterpret_cast<const fp16x8*>(abase + (0 * 4 + s4) * SEG_BYTES + ln * 16);
                fp16x8 a1 = *reinterpret_cast<const fp16x8*>(abase + (1 * 4 + s4) * SEG_BYTES + ln * 16);
                p0 = __builtin_amdgcn_mfma_f32_32x32x16_f16(a0, tf[0][s4], p0, 0, 0, 0);
                p1 = __builtin_amdgcn_mfma_f32_32x32x16_f16(a0, tf[1][s4], p1, 0, 0, 0);
                p2 = __builtin_amdgcn_mfma_f32_32x32x16_f16(a1, tf[0][s4], p2, 0, 0, 0);
            }

            // collapse + per-lane argmin over 16 code-rows; idx ascending in r -> strict <
            #pragma unroll
            for (int r = 0; r < 16; ++r) {
                float v = (p0[r] + p1[r]) + p2[r];           // 0.5|c|^2 - dot
                int idx = chbase + 8 * (r >> 2) + 4 * l5 + (r & 3);  // verified 32x32 C/D row map
                if (v < minv) { minv = v; mini = idx; }
            }
        }

        __syncthreads();   // drains prefetch (vmcnt 0) + protects slot reuse
    }

    // ---- merge l5 halves within wave, then kw halves across waves ----
    {
        float ov = __shfl_xor(minv, 32, 64);
        int   oi = __shfl_xor(mini, 32, 64);
        if (ov < minv || (ov == minv && oi < mini)) { minv = ov; mini = oi; }
        if (ln < 32) {
            redv[kw][tw * 32 + ln] = minv;
            redi[kw][tw * 32 + ln] = mini;
        }
    }
    __syncthreads();

    if (tid < 128) {
        float v0 = redv[0][tid]; int i0 = redi[0][tid];
        float v1 = redv[1][tid]; int i1 = redi[1][tid];
        int bi = (v1 < v0 || (v1 == v0 && i1 < i0)) ? i1 : i0;
        kidx_s[tid] = bi;
        out[IDX_OFF + tok0 + tid] = (float)bi;
    }
    __syncthreads();

    // ---- epilogue: quant (STE form) + loss partial; x re-read (L2/L3-warm) ----
    {
        const int i  = tid & 127;
        const int c0 = tid >> 7;                  // 0..3, 16 channels each
        const int kk = kidx_s[i];
        const float* crow = cb + kk * C_DIM;      // L2-resident gather
        float lsum = 0.f;
        #pragma unroll
        for (int j = 0; j < 16; ++j) {
            int c = c0 * 16 + j;
            float q  = crow[c];
            float xv = x[((b * C_DIM + c) << 10) + hw0 + i];
            float d  = q - xv;                    // (quant - xt)
            lsum = fmaf(d, d, lsum);
            out[QUANT_OFF + ((b * C_DIM + c) << 10) + hw0 + i] = xv + d;  // xt + sg(q-x)
        }
        #pragma unroll
        for (int off = 32; off > 0; off >>= 1)
            lsum += __shfl_down(lsum, off, 64);
        if ((tid & 63) == 0)
            atomicAdd(&ws_sum[blockIdx.x & 7], (double)lsum);
    }
}

// ---------------- fallback (round-2-verified VALU path, used if ws too small) ----------------
#define CB_PAD 68
__global__ __launch_bounds__(256, 2) void vq_main_valu(
    const float* __restrict__ x,
    const float* __restrict__ cb,
    float* __restrict__ out,
    double* __restrict__ ws_sum)
{
    __shared__ float xt_s[C_DIM][128];
    __shared__ float cb_s[C_DIM][CB_PAD];
    __shared__ float cbsq_all[K_CODES];
    __shared__ float red_v[8][128];
    __shared__ int   red_i[8][128];
    __shared__ int   kidx_s[128];

    const int tid  = threadIdx.x;
    const int tok0 = blockIdx.x * 128;
    const int b_img = tok0 >> 10;
    const int hw0   = tok0 & 1023;

    #pragma unroll
    for (int r = 0; r < 4; ++r) {
        int k = tid + r * 256;
        const float4* row = reinterpret_cast<const float4*>(cb + k * C_DIM);
        float s = 0.f;
        #pragma unroll
        for (int j = 0; j < 16; ++j) {
            float4 v = row[j];
            s = fmaf(v.x, v.x, s); s = fmaf(v.y, v.y, s);
            s = fmaf(v.z, v.z, s); s = fmaf(v.w, v.w, s);
        }
        cbsq_all[k] = s;
    }
    {
        const int i  = tid & 127;
        const int c0 = tid >> 7;
        #pragma unroll
        for (int j = 0; j < 32; ++j) {
            int c = c0 + 2 * j;
            xt_s[c][i] = x[((b_img * C_DIM + c) << 10) + hw0 + i];
        }
    }

    const int tl = tid & 31;
    const int kg = tid >> 5;
    float minv[4]; int mini[4];
    #pragma unroll
    for (int m = 0; m < 4; ++m) { minv[m] = 3.4e38f; mini[m] = 0; }

    for (int ch = 0; ch < 16; ++ch) {
        __syncthreads();
        for (int t = tid; t < 64 * C_DIM; t += 256) {
            int kl = t >> 6, c = t & 63;
            cb_s[c][kl] = cb[(ch * 64 + kl) * C_DIM + c];
        }
        __syncthreads();
        float dot[4][8];
        #pragma unroll
        for (int m = 0; m < 4; ++m)
            #pragma unroll
            for (int k = 0; k < 8; ++k) dot[m][k] = 0.f;
        #pragma unroll 4
        for (int c = 0; c < C_DIM; ++c) {
            float4 xv  = *reinterpret_cast<const float4*>(&xt_s[c][tl * 4]);
            float4 cv0 = *reinterpret_cast<const float4*>(&cb_s[c][kg * 8]);
            float4 cv1 = *reinterpret_cast<const float4*>(&cb_s[c][kg * 8 + 4]);
            float xa[4] = {xv.x, xv.y, xv.z, xv.w};
            float ca[8] = {cv0.x, cv0.y, cv0.z, cv0.w, cv1.x, cv1.y, cv1.z, cv1.w};
            #pragma unroll
            for (int m = 0; m < 4; ++m)
                #pragma unroll
                for (int k = 0; k < 8; ++k)
                    dot[m][k] = fmaf(xa[m], ca[k], dot[m][k]);
        }
        const int codebase = ch * 64 + kg * 8;
        #pragma unroll
        for (int k = 0; k < 8; ++k) {
            float csq = cbsq_all[codebase + k];
            #pragma unroll
            for (int m = 0; m < 4; ++m) {
                float sc = fmaf(-2.f, dot[m][k], csq);
                if (sc < minv[m]) { minv[m] = sc; mini[m] = codebase + k; }
            }
        }
    }
    #pragma unroll
    for (int m = 0; m < 4; ++m) {
        red_v[kg][tl * 4 + m] = minv[m];
        red_i[kg][tl * 4 + m] = mini[m];
    }
    __syncthreads();
    if (tid < 128) {
        float bv = red_v[0][tid]; int bi = red_i[0][tid];
        #pragma unroll
        for (int g = 1; g < 8; ++g) {
            float v = red_v[g][tid]; int ii = red_i[g][tid];
            if (v < bv || (v == bv && ii < bi)) { bv = v; bi = ii; }
        }
        kidx_s[tid] = bi;
        out[IDX_OFF + tok0 + tid] = (float)bi;
    }
    __syncthreads();
    {
        const int i  = tid & 127;
        const int c0 = tid >> 7;
        const int kk = kidx_s[i];
        const float* crow = cb + kk * C_DIM;
        float lsum = 0.f;
        #pragma unroll
        for (int j = 0; j < 32; ++j) {
            int c = c0 * 32 + j;
            float q  = crow[c];
            float xv = xt_s[c][i];
            float d  = q - xv;
            lsum = fmaf(d, d, lsum);
            out[QUANT_OFF + ((b_img * C_DIM + c) << 10) + hw0 + i] = xv + d;
        }
        #pragma unroll
        for (int off = 32; off > 0; off >>= 1)
            lsum += __shfl_down(lsum, off, 64);
        if ((tid & 63) == 0)
            atomicAdd(&ws_sum[blockIdx.x & 7], (double)lsum);
    }
}

__global__ void vq_finalize(const double* __restrict__ ws_sum,
                            float* __restrict__ out)
{
    double s = 0.0;
    #pragma unroll
    for (int j = 0; j < 8; ++j) s += ws_sum[j];
    float m = (float)(s / 4194304.0);
    out[LOSS_OFF]     = m;   // loss_embed
    out[LOSS_OFF + 1] = m;   // loss_commitment (identical forward value)
}

__global__ void vq_zero8(double* __restrict__ ws_sum)
{
    if (threadIdx.x < 8) ws_sum[threadIdx.x] = 0.0;
}

extern "C" void kernel_launch(void* const* d_in, const int* in_sizes, int n_in,
                              void* d_out, int out_size, void* d_ws, size_t ws_size,
                              hipStream_t stream) {
    const float* x  = (const float*)d_in[0];
    const float* cb = (const float*)d_in[1];
    float* out      = (float*)d_out;

    if (ws_size >= (size_t)WS_NEEDED) {
        vq_prep<<<272, 64, 0, stream>>>(cb, (float*)d_ws);   // also zeros loss sums
        vq_main<<<512, 512, 0, stream>>>(x, cb, (const float*)d_ws, out, (double*)d_ws);
    } else {
        vq_zero8<<<1, 64, 0, stream>>>((double*)d_ws);
        vq_main_valu<<<512, 256, 0, stream>>>(x, cb, out, (double*)d_ws);
    }
    vq_finalize<<<1, 1, 0, stream>>>((const double*)d_ws, out);
}